// Round 8
// baseline (17823.424 us; speedup 1.0000x reference)
//
#include <hip/hip_runtime.h>

// ---------------- problem constants ----------------
#define BATCH 64
#define SLEN  512
#define EDIM  512
#define HDIM  1024
#define NBLK  256
#define HALF  128                // blocks per layer group
#define K0    (EDIM + HDIM)      // 1536  layer0 K
#define K1    (2 * HDIM)         // 2048  layer1 K
#define ROWB  4096               // LDS bytes per weight row
#define ZR    32                 // z-rows per block = 4 gates x 8 h-cols
#define ZST   68                 // zbuf batch-row stride (2 nt-partials of 34)
#define HB    (BATCH * HDIM)     // elems per h slot (65536; 128 KiB bf16)
#define RING  8                  // fallback ring depth

#define PA_STEPS 1024            // probe_nosync steps (xe index masked by SLEN-1)

#define XE_BYTES ((size_t)SLEN * BATCH * EDIM * 2)      // 32 MiB
#define HBUF_BIG ((size_t)SLEN * HB * 2)                // 64 MiB per layer
#define HBUF_SML ((size_t)RING * HB * 2)                // 1 MiB per layer

typedef __bf16 bf16x8 __attribute__((ext_vector_type(8)));
typedef float  f32x4  __attribute__((ext_vector_type(4)));
typedef unsigned u32x4 __attribute__((ext_vector_type(4)));

__device__ __forceinline__ float sigm(float x) { return 1.0f / (1.0f + __expf(-x)); }
__device__ __forceinline__ float tanhfast(float x) {
  float e = __expf(-2.0f * __builtin_fabsf(x));
  float r = (1.0f - e) / (1.0f + e);
  return x < 0.0f ? -r : r;
}

// 16B write-through store (visible at L3 once vmcnt drains; never dirty in L2)
__device__ __forceinline__ void st16_wt(__bf16* p, unsigned d0, unsigned d1,
                                        unsigned d2, unsigned d3) {
  u32x4 v = {d0, d1, d2, d3};
  asm volatile("global_store_dwordx4 %0, %1, off sc0 sc1" :: "v"(p), "v"(v) : "memory");
}

// L2-bypassing 16B load (fallback ring path only)
__device__ __forceinline__ bf16x8 ald16(const __bf16* p) {
  union { unsigned long long q[2]; bf16x8 v; } u;
  u.q[0] = __hip_atomic_load((const unsigned long long*)p,       __ATOMIC_RELAXED, __HIP_MEMORY_SCOPE_AGENT);
  u.q[1] = __hip_atomic_load((const unsigned long long*)(p + 4), __ATOMIC_RELAXED, __HIP_MEMORY_SCOPE_AGENT);
  return u.v;
}

template<int BIG>
__device__ __forceinline__ bf16x8 hload(const __bf16* p) {
  if constexpr (BIG) return *(const bf16x8*)p;   // normal load: L2-cached, multicast
  else return ald16(p);                          // ring mode: must bypass (slot reuse)
}

// Block-level wait. FMA heater in both spin paths: keeps VALU power up during
// waits (DPM clock-droop hypothesis); ~50ns extra detect granularity.
__device__ __forceinline__ void block_wait(const int* f, int target, int* gate) {
  if (target <= 0) return;
  float hx = 1.0f;
  if ((threadIdx.x >> 6) == 0) {
    if (__hip_atomic_load(gate, __ATOMIC_RELAXED, __HIP_MEMORY_SCOPE_WORKGROUP) < target) {
      const int l = threadIdx.x & 63;
      int tries = 0;
      while (true) {
        int v0 = __hip_atomic_load(f + l,      __ATOMIC_RELAXED, __HIP_MEMORY_SCOPE_AGENT);
        int v1 = __hip_atomic_load(f + l + 64, __ATOMIC_RELAXED, __HIP_MEMORY_SCOPE_AGENT);
        if (__all((v0 >= target) && (v1 >= target))) break;
        #pragma unroll
        for (int j = 0; j < 32; ++j) hx = __builtin_fmaf(hx, 1.0000001f, 1e-9f);
        if (++tries > (1 << 21)) break;   // anti-hang safety net
      }
      if (l == 0)
        __hip_atomic_fetch_max(gate, target, __ATOMIC_RELEASE, __HIP_MEMORY_SCOPE_WORKGROUP);
    }
  } else {
    int tries = 0;
    while (__hip_atomic_load(gate, __ATOMIC_ACQUIRE, __HIP_MEMORY_SCOPE_WORKGROUP) < target) {
      #pragma unroll
      for (int j = 0; j < 32; ++j) hx = __builtin_fmaf(hx, 1.0000001f, 1e-9f);
      if (++tries > (1 << 21)) break;
    }
  }
  asm volatile("" :: "v"(hx));   // keep heater live (rule #17)
}

// ---- xe = bf16(emb[x]) laid out [t][b][e] ----
__global__ void xe_gather(const int* __restrict__ x, const float* __restrict__ emb,
                          __bf16* __restrict__ xe) {
  int g = blockIdx.x * blockDim.x + threadIdx.x;
  if (g >= SLEN * BATCH * (EDIM / 8)) return;
  int e8 = g & 63, bt = g >> 6;
  int b = bt & 63, t = bt >> 6;
  int tok = x[b * SLEN + t];
  const float* er = emb + (size_t)tok * EDIM + e8 * 8;
  f32x4 v0 = *(const f32x4*)er, v1 = *(const f32x4*)(er + 4);
  bf16x8 o = { (__bf16)v0[0], (__bf16)v0[1], (__bf16)v0[2], (__bf16)v0[3],
               (__bf16)v1[0], (__bf16)v1[1], (__bf16)v1[2], (__bf16)v1[3] };
  *(bf16x8*)(xe + ((size_t)t * BATCH + b) * EDIM + e8 * 8) = o;
}

// ===================== PROBE: effective-clock calibration ====================
// 2,097,152 dependent v_fma_f32 @ 4 cy/FMA = 8.39M cycles.
// Expected dur: ~3.5 ms @ 2.4 GHz | ~14 ms @ 600 MHz. Reads SCLK from dur_us.
__global__ void probe_clock(float* sink) {
  float x = 1.0f + 1e-7f * (float)threadIdx.x;
  for (int i = 0; i < 32768; ++i) {
    #pragma unroll
    for (int j = 0; j < 64; ++j) x = __builtin_fmaf(x, 1.0000001f, 1e-9f);
  }
  if (x == 0.0f) sink[0] = x;   // never true; keeps chain live
}

// ---------------- shared macros (real kernel and probe_nosync) --------------
#define LDSB(brb, koff) (*(const bf16x8*)(&Ws[(brb) + (((unsigned)((((koff) << 1)) + (q << 4))) ^ bsw)]))
#define MFMA(a, b, c) __builtin_amdgcn_mfma_f32_16x16x32_bf16(a, b, c, 0, 0, 0)

#define STAGE_WEIGHTS()                                                           \
  do {                                                                            \
    if (layer == 0) {                                                             \
      for (int idx = tid; idx < ZR * K0; idx += 512) {                            \
        int n = idx / K0, k = idx - n * K0;                                       \
        int grow = (n >> 3) * HDIM + sub * 8 + (n & 7);                           \
        float v = (k < EDIM) ? Wx0[grow * EDIM + k] : Wh0[grow * HDIM + (k - EDIM)]; \
        *(__bf16*)(&Ws[n * ROWB + (((unsigned)(k << 1)) ^ (unsigned)((n & 7) << 4))]) = (__bf16)v; \
      }                                                                           \
      if (tid < ZR) {                                                             \
        int grow = (tid >> 3) * HDIM + sub * 8 + (tid & 7);                       \
        bias[tid] = bx0[grow] + bh0[grow];                                        \
      }                                                                           \
    } else {                                                                      \
      for (int idx = tid; idx < ZR * K1; idx += 512) {                            \
        int n = idx >> 11, k = idx & (K1 - 1);                                    \
        int grow = (n >> 3) * HDIM + sub * 8 + (n & 7);                           \
        float v = (k < HDIM) ? Wx1[grow * HDIM + k] : Wh1[grow * HDIM + (k - HDIM)]; \
        *(__bf16*)(&Ws[n * ROWB + (((unsigned)(k << 1)) ^ (unsigned)((n & 7) << 4))]) = (__bf16)v; \
      }                                                                           \
      if (tid < ZR) {                                                             \
        int grow = (tid >> 3) * HDIM + sub * 8 + (tid & 7);                       \
        bias[tid] = bx1[grow] + bh1[grow];                                        \
      }                                                                           \
    }                                                                             \
  } while (0)

#define XE_PART(sidx, A0, A1)                                                     \
  do {                                                                            \
    if (use_xe) {                                                                 \
      const __bf16* aX = xe + ((size_t)(sidx) * BATCH + brow) * EDIM;             \
      _Pragma("unroll 4")                                                         \
      for (int k0 = nt * 32; k0 < EDIM; k0 += 64) {                               \
        bf16x8 a = *(const bf16x8*)(aX + k0 + q * 8);                             \
        A0 = MFMA(a, LDSB(brb0, k0), A0);                                         \
        A1 = MFMA(a, LDSB(brb1, k0), A1);                                         \
      }                                                                           \
    } else {                                                                      \
      const int tok = x[brow * SLEN + (sidx)];                                    \
      const float* erow = emb + (size_t)tok * EDIM;                               \
      _Pragma("unroll 4")                                                         \
      for (int k0 = nt * 32; k0 < EDIM; k0 += 64) {                               \
        f32x4 e0 = *(const f32x4*)(erow + k0 + q * 8);                            \
        f32x4 e1 = *(const f32x4*)(erow + k0 + q * 8 + 4);                        \
        bf16x8 a = { (__bf16)e0[0], (__bf16)e0[1], (__bf16)e0[2], (__bf16)e0[3],  \
                     (__bf16)e1[0], (__bf16)e1[1], (__bf16)e1[2], (__bf16)e1[3] };\
        A0 = MFMA(a, LDSB(brb0, k0), A0);                                         \
        A1 = MFMA(a, LDSB(brb1, k0), A1);                                         \
      }                                                                           \
    }                                                                             \
  } while (0)

#define ZWRITE()                                                                  \
  do {                                                                            \
    _Pragma("unroll")                                                             \
    for (int r = 0; r < 4; ++r) {                                                 \
      zbuf[(zrow + r) * ZST + nt * 34 + mrow]      = acc0[r];                     \
      zbuf[(zrow + r) * ZST + nt * 34 + 16 + mrow] = acc1[r];                     \
    }                                                                             \
  } while (0)

#define EPILOGUE(hdst, slotExpr)                                                  \
  do {                                                                            \
    float zf = zbuf[bg*ZST +      jl] + zbuf[bg*ZST + 34 +      jl] + bias[     jl]; \
    float zi = zbuf[bg*ZST +  8 + jl] + zbuf[bg*ZST + 34 +  8 + jl] + bias[ 8 + jl]; \
    float zg = zbuf[bg*ZST + 16 + jl] + zbuf[bg*ZST + 34 + 16 + jl] + bias[16 + jl]; \
    float zo = zbuf[bg*ZST + 24 + jl] + zbuf[bg*ZST + 34 + 24 + jl] + bias[24 + jl]; \
    float fg = sigm(zf), ig = sigm(zi), gg = tanhfast(zg), og = sigm(zo);         \
    cst = fg * cst + ig * gg;                                                     \
    __bf16 hv = (__bf16)(og * tanhfast(cst));                                     \
    unsigned short us = __builtin_bit_cast(unsigned short, hv);                   \
    unsigned pw = ((unsigned)us) | (((unsigned)(unsigned short)__shfl_xor((int)us, 1, 64)) << 16); \
    unsigned d1 = (unsigned)__shfl_xor((int)pw, 2, 64);                           \
    unsigned d2 = (unsigned)__shfl_xor((int)pw, 4, 64);                           \
    unsigned d3 = (unsigned)__shfl_xor((int)pw, 6, 64);                           \
    if (jl == 0)                                                                  \
      st16_wt(hdst + (slotExpr) + bg * HDIM + sub * 8, pw, d1, d2, d3);           \
    asm volatile("s_waitcnt vmcnt(0)" ::: "memory");                              \
  } while (0)

#define THREAD_GEOMETRY()                                                         \
  const int lane = tid & 63, wave = tid >> 6;                                     \
  const int mrow = lane & 15;                                                     \
  const int q    = lane >> 4;                                                     \
  const int mt   = wave >> 1, nt = wave & 1;                                      \
  const int brow = mt * 16 + mrow;                                                \
  const unsigned brb0 = (unsigned)(mrow * ROWB);                                  \
  const unsigned brb1 = (unsigned)((16 + mrow) * ROWB);                           \
  const unsigned bsw  = (unsigned)((mrow & 7) << 4);                              \
  const int bg = tid >> 3, jl = tid & 7;                                          \
  const int zrow = mt * 16 + q * 4

// ===================== PROBE: compute/memory only, no cross-block sync ======
__global__ __launch_bounds__(512, 2) void probe_nosync(
    const int* __restrict__ x, const float* __restrict__ emb,
    const float* __restrict__ Wx0, const float* __restrict__ bx0,
    const float* __restrict__ Wh0, const float* __restrict__ bh0,
    const float* __restrict__ Wx1, const float* __restrict__ bx1,
    const float* __restrict__ Wh1, const float* __restrict__ bh1,
    const __bf16* __restrict__ xe, int use_xe,
    __bf16* h0buf, __bf16* h1buf)
{
  __shared__ __align__(16) unsigned char Ws[ZR * ROWB];
  __shared__ float zbuf[BATCH * ZST];
  __shared__ float bias[ZR];
  const int tid = threadIdx.x;
  const int wg = blockIdx.x, layer = wg >> 7, sub = wg & (HALF - 1);
  STAGE_WEIGHTS();
  __syncthreads();
  THREAD_GEOMETRY();
  float cst = 0.0f;
#define PSLOT(s) ((size_t)((s) & 3) * HB)
  if (layer == 0) {
    for (int s = 0; s < PA_STEPS; ++s) {
      const int t = s & (SLEN - 1);
      f32x4 acc0 = {0.f,0.f,0.f,0.f}, acc1 = {0.f,0.f,0.f,0.f};
      XE_PART(t, acc0, acc1);
      if (s > 0) {
        const __bf16* hp = h0buf + PSLOT(s - 1) + brow * HDIM + nt * 32 + q * 8;
        const int kb = EDIM + nt * 32;
        #pragma unroll
        for (int i = 0; i < 16; ++i) {
          bf16x8 a = *(const bf16x8*)(hp + i * 64);
          acc0 = MFMA(a, LDSB(brb0, kb + i*64), acc0);
          acc1 = MFMA(a, LDSB(brb1, kb + i*64), acc1);
        }
      }
      ZWRITE();
      __syncthreads();
      EPILOGUE(h0buf, PSLOT(s));
      __syncthreads();
    }
  } else {
    for (int j = 0; j < PA_STEPS; ++j) {
      f32x4 acc0 = {0.f,0.f,0.f,0.f}, acc1 = {0.f,0.f,0.f,0.f};
      if (j > 0) {
        const __bf16* hp = h1buf + PSLOT(j - 1) + brow * HDIM + nt * 32 + q * 8;
        const int kb = HDIM + nt * 32;
        #pragma unroll
        for (int i = 0; i < 16; ++i) {
          bf16x8 a = *(const bf16x8*)(hp + i * 64);
          acc0 = MFMA(a, LDSB(brb0, kb + i*64), acc0);
          acc1 = MFMA(a, LDSB(brb1, kb + i*64), acc1);
        }
      }
      {
        const __bf16* hp = h0buf + PSLOT(j) + brow * HDIM + nt * 32 + q * 8;
        const int kb = nt * 32;
        #pragma unroll
        for (int i = 0; i < 16; ++i) {
          bf16x8 a = *(const bf16x8*)(hp + i * 64);
          acc0 = MFMA(a, LDSB(brb0, kb + i*64), acc0);
          acc1 = MFMA(a, LDSB(brb1, kb + i*64), acc1);
        }
      }
      ZWRITE();
      __syncthreads();
      EPILOGUE(h1buf, PSLOT(j));
      __syncthreads();
    }
  }
}

// ===================== REAL KERNEL (R5 config + heater spins) ===============
template<int BIG>
__global__ __launch_bounds__(512, 2) void lstm_persistent(
    const int* __restrict__ x, const float* __restrict__ emb,
    const float* __restrict__ Wx0, const float* __restrict__ bx0,
    const float* __restrict__ Wh0, const float* __restrict__ bh0,
    const float* __restrict__ Wx1, const float* __restrict__ bx1,
    const float* __restrict__ Wh1, const float* __restrict__ bh1,
    const __bf16* __restrict__ xe, int use_xe,
    __bf16* h0buf, __bf16* h1buf, int* f0, int* f1)
{
  __shared__ __align__(16) unsigned char Ws[ZR * ROWB];   // 128 KiB
  __shared__ float zbuf[BATCH * ZST];                     // 17 KiB
  __shared__ float bias[ZR];
  __shared__ int gateF0, gateF1;

  const int tid   = threadIdx.x;
  const int wg    = blockIdx.x;
  const int layer = wg >> 7;
  const int sub   = wg & (HALF - 1);

  if (tid == 0) { gateF0 = 0; gateF1 = 0; }
  STAGE_WEIGHTS();
  __syncthreads();
  THREAD_GEOMETRY();
  float cst = 0.0f;

#define SLOT(s)  ((size_t)(BIG ? (s) : ((s) & (RING - 1))) * HB)

  if (layer == 0) {
    for (int s = 0; s < SLEN; ++s) {
      f32x4 acc0 = {0.f,0.f,0.f,0.f}, acc1 = {0.f,0.f,0.f,0.f};
      XE_PART(s, acc0, acc1);
      if (s > 0) {
        block_wait(f0, s, &gateF0);
        const __bf16* hp = h0buf + SLOT(s - 1) + brow * HDIM + nt * 32 + q * 8;
        const int kb = EDIM + nt * 32;
        #pragma unroll
        for (int i = 0; i < 16; ++i) {
          bf16x8 a = hload<BIG>(hp + i * 64);
          acc0 = MFMA(a, LDSB(brb0, kb + i*64), acc0);
          acc1 = MFMA(a, LDSB(brb1, kb + i*64), acc1);
        }
      }
      ZWRITE();
      __syncthreads();
      if constexpr (!BIG) {
        if (s >= RING) { block_wait(f1, s - RING + 2, &gateF1); block_wait(f0, s - RING + 2, &gateF0); }
      }
      EPILOGUE(h0buf, SLOT(s));
      __syncthreads();
      if (tid == 0)
        __hip_atomic_store(&f0[sub], s + 1, __ATOMIC_RELAXED, __HIP_MEMORY_SCOPE_AGENT);
    }
  } else {
    for (int j = 0; j < SLEN; ++j) {
      f32x4 acc0 = {0.f,0.f,0.f,0.f}, acc1 = {0.f,0.f,0.f,0.f};
      if (j > 0) {
        block_wait(f1, j, &gateF1);
        const __bf16* hp = h1buf + SLOT(j - 1) + brow * HDIM + nt * 32 + q * 8;
        const int kb = HDIM + nt * 32;
        #pragma unroll
        for (int i = 0; i < 16; ++i) {
          bf16x8 a = hload<BIG>(hp + i * 64);
          acc0 = MFMA(a, LDSB(brb0, kb + i*64), acc0);
          acc1 = MFMA(a, LDSB(brb1, kb + i*64), acc1);
        }
      }
      block_wait(f0, j + 1, &gateF0);
      {
        const __bf16* hp = h0buf + SLOT(j) + brow * HDIM + nt * 32 + q * 8;
        const int kb = nt * 32;
        #pragma unroll
        for (int i = 0; i < 16; ++i) {
          bf16x8 a = hload<BIG>(hp + i * 64);
          acc0 = MFMA(a, LDSB(brb0, kb + i*64), acc0);
          acc1 = MFMA(a, LDSB(brb1, kb + i*64), acc1);
        }
      }
      ZWRITE();
      __syncthreads();
      if constexpr (!BIG) {
        if (j >= RING) block_wait(f1, j - RING + 2, &gateF1);
      }
      EPILOGUE(h1buf, SLOT(j));
      __syncthreads();
      if (tid == 0)
        __hip_atomic_store(&f1[sub], j + 1, __ATOMIC_RELAXED, __HIP_MEMORY_SCOPE_AGENT);
    }
  }
}

// ---- final FC: out[b] = sigmoid(h1(511) . fcw + fcb) ----
__global__ void fc_kernel(const __bf16* __restrict__ h1slot,
                          const float* __restrict__ fcw, const float* __restrict__ fcb,
                          float* __restrict__ out) {
  __shared__ float part[512];
  const int tid = threadIdx.x, b = tid >> 3, q2 = tid & 7;
  const __bf16* hr = h1slot + b * HDIM + q2 * 128;
  const float*  wr = fcw + q2 * 128;
  float acc = 0.0f;
  for (int k = 0; k < 128; k += 8) {
    bf16x8 hvv = *(const bf16x8*)(hr + k);
    #pragma unroll
    for (int i = 0; i < 8; ++i) acc += (float)hvv[i] * wr[k + i];
  }
  part[tid] = acc;
  __syncthreads();
  if (tid < BATCH) {
    float s = fcb[0];
    #pragma unroll
    for (int i = 0; i < 8; ++i) s += part[tid * 8 + i];
    out[tid] = 1.0f / (1.0f + __expf(-s));
  }
}

extern "C" void kernel_launch(void* const* d_in, const int* in_sizes, int n_in,
                              void* d_out, int out_size, void* d_ws, size_t ws_size,
                              hipStream_t stream) {
  (void)in_sizes; (void)n_in; (void)out_size;
  const int*   x   = (const int*)  d_in[0];
  const float* emb = (const float*)d_in[1];
  const float* Wx0 = (const float*)d_in[2];
  const float* bx0 = (const float*)d_in[3];
  const float* Wh0 = (const float*)d_in[4];
  const float* bh0 = (const float*)d_in[5];
  const float* Wx1 = (const float*)d_in[6];
  const float* bx1 = (const float*)d_in[7];
  const float* Wh1 = (const float*)d_in[8];
  const float* bh1 = (const float*)d_in[9];
  const float* fcw = (const float*)d_in[10];
  const float* fcb = (const float*)d_in[11];
  float* out = (float*)d_out;

  char* ws = (char*)d_ws;
  int*   f0   = (int*)(ws);
  int*   f1   = (int*)(ws + 512);
  float* sink = (float*)(ws + 2048);

  const size_t need_big = 4096 + 2 * HBUF_BIG + XE_BYTES;           // ~160.1 MiB
  const size_t need_sml = 4096 + 2 * HBUF_SML + XE_BYTES;           // ~34.1 MiB
  const int big    = (ws_size >= need_big) ? 1 : 0;
  const size_t hbytes = big ? HBUF_BIG : HBUF_SML;
  __bf16* h0buf = (__bf16*)(ws + 4096);
  __bf16* h1buf = (__bf16*)(ws + 4096 + hbytes);
  __bf16* xe    = (__bf16*)(ws + 4096 + 2 * hbytes);
  const int use_xe = (big || ws_size >= need_sml) ? 1 : 0;

  hipMemsetAsync(d_ws, 0, 4096, stream);   // flags
  // ---- clock probe first: samples post-replay DPM state ----
  probe_clock<<<1, 64, 0, stream>>>(sink);
  if (use_xe) {
    const int groups = SLEN * BATCH * (EDIM / 8);
    xe_gather<<<(groups + 255) / 256, 256, 0, stream>>>(x, emb, xe);
  }
  // ---- compute-structure probe (scratch slots 0..3; real kernel overwrites
  //      before reading, so correctness unaffected) ----
  probe_nosync<<<NBLK, 512, 0, stream>>>(x, emb, Wx0, bx0, Wh0, bh0,
                                         Wx1, bx1, Wh1, bh1,
                                         xe, use_xe, h0buf, h1buf);

  if (big) {
    lstm_persistent<1><<<NBLK, 512, 0, stream>>>(x, emb, Wx0, bx0, Wh0, bh0,
                                                 Wx1, bx1, Wh1, bh1,
                                                 xe, use_xe, h0buf, h1buf, f0, f1);
    fc_kernel<<<1, 512, 0, stream>>>(h1buf + (size_t)(SLEN - 1) * HB, fcw, fcb, out);
  } else {
    lstm_persistent<0><<<NBLK, 512, 0, stream>>>(x, emb, Wx0, bx0, Wh0, bh0,
                                                 Wx1, bx1, Wh1, bh1,
                                                 xe, use_xe, h0buf, h1buf, f0, f1);
    fc_kernel<<<1, 512, 0, stream>>>(h1buf + (size_t)((SLEN - 1) & (RING - 1)) * HB, fcw, fcb, out);
  }
}

// Round 9
// 7170.824 us; speedup vs baseline: 2.4855x; 2.4855x over previous
//
#include <hip/hip_runtime.h>

// ---------------- problem constants ----------------
#define BATCH 64
#define SLEN  512
#define EDIM  512
#define HDIM  1024
#define NBLK  256
#define HALF  128                // blocks per layer group
#define K0    1536               // layer0 K  (xe 512 | h0 1024)
#define K1    2048               // layer1 K  (h0' 1024 | h1 1024)
#define KS0   (K0 / 16)          // 96 k-steps of 16
#define KS1   (K1 / 16)          // 128
#define RST   136                // zbuf row stride (f16 units): 4 parts x 32 cols + 8 pad
#define HB    (BATCH * HDIM)     // elems per h slot (128 KiB bf16)
#define RING  8                  // fallback ring depth

#define XE_BYTES ((size_t)SLEN * BATCH * EDIM * 2)      // 32 MiB
#define HBUF_BIG ((size_t)SLEN * HB * 2)                // 64 MiB per layer
#define HBUF_SML ((size_t)RING * HB * 2)                // 1 MiB per layer

typedef __bf16 bf16x8 __attribute__((ext_vector_type(8)));
typedef float  f32x4  __attribute__((ext_vector_type(4)));
typedef float  f32x16 __attribute__((ext_vector_type(16)));
typedef unsigned u32x4 __attribute__((ext_vector_type(4)));

__device__ __forceinline__ float sigm(float x) { return 1.0f / (1.0f + __expf(-x)); }
__device__ __forceinline__ float tanhfast(float x) {
  float e = __expf(-2.0f * __builtin_fabsf(x));
  float r = (1.0f - e) / (1.0f + e);
  return x < 0.0f ? -r : r;
}

// 16B write-through store (visible at L3 once vmcnt drains; never dirty in L2)
__device__ __forceinline__ void st16_wt(__bf16* p, unsigned d0, unsigned d1,
                                        unsigned d2, unsigned d3) {
  u32x4 v = {d0, d1, d2, d3};
  asm volatile("global_store_dwordx4 %0, %1, off sc0 sc1" :: "v"(p), "v"(v) : "memory");
}

// L2-bypassing 16B load (fallback ring path only)
__device__ __forceinline__ bf16x8 ald16(const __bf16* p) {
  union { unsigned long long q[2]; bf16x8 v; } u;
  u.q[0] = __hip_atomic_load((const unsigned long long*)p,       __ATOMIC_RELAXED, __HIP_MEMORY_SCOPE_AGENT);
  u.q[1] = __hip_atomic_load((const unsigned long long*)(p + 4), __ATOMIC_RELAXED, __HIP_MEMORY_SCOPE_AGENT);
  return u.v;
}

template<int BIG>
__device__ __forceinline__ bf16x8 hload(const __bf16* p) {
  if constexpr (BIG) return *(const bf16x8*)p;   // normal load: L2-cached, multicast
  else return ald16(p);                          // ring mode: must bypass (slot reuse)
}

// Per-wave wait: all lanes poll the 128 layer flags (2 per lane), s_sleep poll.
__device__ __forceinline__ void wave_wait(const int* f, int target) {
  if (target <= 0) return;
  const int l = threadIdx.x & 63;
  int tries = 0;
  while (true) {
    int v0 = __hip_atomic_load(f + l,      __ATOMIC_RELAXED, __HIP_MEMORY_SCOPE_AGENT);
    int v1 = __hip_atomic_load(f + l + 64, __ATOMIC_RELAXED, __HIP_MEMORY_SCOPE_AGENT);
    if (__all((v0 >= target) && (v1 >= target))) return;
    __builtin_amdgcn_s_sleep(1);
    if (++tries > (1 << 21)) return;   // anti-hang safety net
  }
}

// ---- xe = bf16(emb[x]) laid out [t][b][e] ----
__global__ void xe_gather(const int* __restrict__ x, const float* __restrict__ emb,
                          __bf16* __restrict__ xe) {
  int g = blockIdx.x * blockDim.x + threadIdx.x;
  if (g >= SLEN * BATCH * (EDIM / 8)) return;
  int e8 = g & 63, bt = g >> 6;
  int b = bt & 63, t = bt >> 6;
  int tok = x[b * SLEN + t];
  const float* er = emb + (size_t)tok * EDIM + e8 * 8;
  f32x4 v0 = *(const f32x4*)er, v1 = *(const f32x4*)(er + 4);
  bf16x8 o = { (__bf16)v0[0], (__bf16)v0[1], (__bf16)v0[2], (__bf16)v0[3],
               (__bf16)v1[0], (__bf16)v1[1], (__bf16)v1[2], (__bf16)v1[3] };
  *(bf16x8*)(xe + ((size_t)t * BATCH + b) * EDIM + e8 * 8) = o;
}

#define MFMA32(a, b, c) __builtin_amdgcn_mfma_f32_32x32x16_bf16(a, b, c, 0, 0, 0)

// Persistent skewed 2-layer LSTM, 32x32x16 MFMA, fragment-major LDS weights.
// Fragment (ks, lane): W[col = lane&31][k = ks*16 + (lane>>5)*8 + i], stored at
// WsB + (ks*64+lane)*16 -> a wave's B-read for one ks is a linear 1024B burst
// (bank-conflict-free). Waves: mt(2 batch 32-row tiles) x nt(4 K-interleave).
template<int BIG>
__global__ __launch_bounds__(512, 2) void lstm_persistent(
    const int* __restrict__ x, const float* __restrict__ emb,
    const float* __restrict__ Wx0, const float* __restrict__ bx0,
    const float* __restrict__ Wh0, const float* __restrict__ bh0,
    const float* __restrict__ Wx1, const float* __restrict__ bx1,
    const float* __restrict__ Wh1, const float* __restrict__ bh1,
    const __bf16* __restrict__ xe, int use_xe,
    __bf16* h0buf, __bf16* h1buf, int* f0, int* f1)
{
  __shared__ __align__(16) unsigned char WsB[KS1 * 64 * 16];  // 128 KiB
  __shared__ _Float16 zbuf[BATCH * RST];                      // 17 KiB
  __shared__ float bias[32];

  const int tid   = threadIdx.x;
  const int wg    = blockIdx.x;
  const int layer = wg >> 7;
  const int sub   = wg & (HALF - 1);

  // ---- stage weights into fragment-major LDS (linear writes) ----
  if (layer == 0) {
    for (int idx = tid; idx < KS0 * 64; idx += 512) {
      int ks = idx >> 6, ln = idx & 63;
      int col = ln & 31;
      int grow = (col >> 3) * HDIM + sub * 8 + (col & 7);
      int k = ks * 16 + (ln >> 5) * 8;
      const float* src = (k < EDIM) ? (Wx0 + (size_t)grow * EDIM + k)
                                    : (Wh0 + (size_t)grow * HDIM + (k - EDIM));
      f32x4 v0 = *(const f32x4*)src, v1 = *(const f32x4*)(src + 4);
      bf16x8 o = { (__bf16)v0[0], (__bf16)v0[1], (__bf16)v0[2], (__bf16)v0[3],
                   (__bf16)v1[0], (__bf16)v1[1], (__bf16)v1[2], (__bf16)v1[3] };
      *(bf16x8*)(WsB + (size_t)idx * 16) = o;
    }
    if (tid < 32) {
      int grow = (tid >> 3) * HDIM + sub * 8 + (tid & 7);
      bias[tid] = bx0[grow] + bh0[grow];
    }
  } else {
    for (int idx = tid; idx < KS1 * 64; idx += 512) {
      int ks = idx >> 6, ln = idx & 63;
      int col = ln & 31;
      int grow = (col >> 3) * HDIM + sub * 8 + (col & 7);
      int k = ks * 16 + (ln >> 5) * 8;
      const float* src = (k < HDIM) ? (Wx1 + (size_t)grow * HDIM + k)
                                    : (Wh1 + (size_t)grow * HDIM + (k - HDIM));
      f32x4 v0 = *(const f32x4*)src, v1 = *(const f32x4*)(src + 4);
      bf16x8 o = { (__bf16)v0[0], (__bf16)v0[1], (__bf16)v0[2], (__bf16)v0[3],
                   (__bf16)v1[0], (__bf16)v1[1], (__bf16)v1[2], (__bf16)v1[3] };
      *(bf16x8*)(WsB + (size_t)idx * 16) = o;
    }
    if (tid < 32) {
      int grow = (tid >> 3) * HDIM + sub * 8 + (tid & 7);
      bias[tid] = bx1[grow] + bh1[grow];
    }
  }
  __syncthreads();

  const int lane  = tid & 63, wave = tid >> 6;
  const int mt    = wave >> 2;          // batch 32-row tile
  const int nt    = wave & 3;           // K interleave class (ks ≡ nt mod 4)
  const int col   = lane & 31;          // A row within tile / B z-col
  const int arow  = mt * 32 + col;      // batch row this lane loads
  const int koff8 = (lane >> 5) * 8;    // k-subgroup offset within fragment
  const int bg    = tid >> 3, jl = tid & 7;   // gate phase: (batch row, h-col)

  float cst = 0.0f;

#define SLOT(s)  ((size_t)(BIG ? (s) : ((s) & (RING - 1))) * HB)
#define LDSB(ks) (*(const bf16x8*)(&WsB[((ks) * 64 + lane) * 16]))

// ZWRITE: C layout col=lane&31, row=(r&3)+8*(r>>2)+4*(lane>>5)  [m74/m101]
#define ZWRITE()                                                                  \
  do {                                                                            \
    _Pragma("unroll")                                                             \
    for (int r = 0; r < 16; ++r) {                                                \
      int zrow = mt * 32 + (r & 3) + 8 * (r >> 2) + 4 * (lane >> 5);              \
      zbuf[zrow * RST + nt * 32 + col] = (_Float16)acc[r];                        \
    }                                                                             \
  } while (0)

// gates (sum 4 nt-partials) -> h value -> packed 16B wt store (jl==0) -> drain
#define EPILOGUE(hdst, slotExpr)                                                  \
  do {                                                                            \
    float zf = 0.f, zi = 0.f, zg = 0.f, zo = 0.f;                                 \
    _Pragma("unroll")                                                             \
    for (int p = 0; p < 4; ++p) {                                                 \
      zf += (float)zbuf[bg * RST + p * 32 +      jl];                             \
      zi += (float)zbuf[bg * RST + p * 32 +  8 + jl];                             \
      zg += (float)zbuf[bg * RST + p * 32 + 16 + jl];                             \
      zo += (float)zbuf[bg * RST + p * 32 + 24 + jl];                             \
    }                                                                             \
    zf += bias[jl]; zi += bias[8 + jl]; zg += bias[16 + jl]; zo += bias[24 + jl]; \
    float fg = sigm(zf), ig = sigm(zi), gg = tanhfast(zg), og = sigm(zo);         \
    cst = fg * cst + ig * gg;                                                     \
    __bf16 hv = (__bf16)(og * tanhfast(cst));                                     \
    unsigned short us = __builtin_bit_cast(unsigned short, hv);                   \
    unsigned pw = ((unsigned)us) | (((unsigned)(unsigned short)__shfl_xor((int)us, 1, 64)) << 16); \
    unsigned d1 = (unsigned)__shfl_xor((int)pw, 2, 64);                           \
    unsigned d2 = (unsigned)__shfl_xor((int)pw, 4, 64);                           \
    unsigned d3 = (unsigned)__shfl_xor((int)pw, 6, 64);                           \
    if (jl == 0)                                                                  \
      st16_wt(hdst + (slotExpr) + bg * HDIM + sub * 8, pw, d1, d2, d3);           \
    asm volatile("s_waitcnt vmcnt(0)" ::: "memory");                              \
  } while (0)

  if (layer == 0) {
    for (int s = 0; s < SLEN; ++s) {
      f32x16 acc = {0.f,0.f,0.f,0.f,0.f,0.f,0.f,0.f,0.f,0.f,0.f,0.f,0.f,0.f,0.f,0.f};
      // --- xe part: ks = nt + 4j, j=0..7 (all < 32 -> k < 512) ---
      if (use_xe) {
        const __bf16* aX = xe + ((size_t)s * BATCH + arow) * EDIM + koff8;
        #pragma unroll
        for (int j = 0; j < 8; ++j) {
          int ks = nt + 4 * j;
          bf16x8 a = *(const bf16x8*)(aX + ks * 16);
          acc = MFMA32(a, LDSB(ks), acc);
        }
      } else {
        const int tok = x[arow * SLEN + s];
        const float* erow = emb + (size_t)tok * EDIM + koff8;
        #pragma unroll
        for (int j = 0; j < 8; ++j) {
          int ks = nt + 4 * j;
          f32x4 e0 = *(const f32x4*)(erow + ks * 16);
          f32x4 e1 = *(const f32x4*)(erow + ks * 16 + 4);
          bf16x8 a = { (__bf16)e0[0], (__bf16)e0[1], (__bf16)e0[2], (__bf16)e0[3],
                       (__bf16)e1[0], (__bf16)e1[1], (__bf16)e1[2], (__bf16)e1[3] };
          acc = MFMA32(a, LDSB(ks), acc);
        }
      }
      // --- h0(s-1) part: ks = nt + 4j, j=8..23 (k in [512,1536)) ---
      if (s > 0) {
        wave_wait(f0, s);
        const __bf16* hp = h0buf + SLOT(s - 1) + (size_t)arow * HDIM + koff8;
        #pragma unroll
        for (int j = 8; j < 24; ++j) {
          int ks = nt + 4 * j;
          bf16x8 a = hload<BIG>(hp + ks * 16 - EDIM);
          acc = MFMA32(a, LDSB(ks), acc);
        }
      }
      ZWRITE();
      __syncthreads();
      if constexpr (!BIG) {   // ring anti-dep: slot reused after RING steps
        if (s >= RING) { wave_wait(f1, s - RING + 2); wave_wait(f0, s - RING + 2); }
      }
      EPILOGUE(h0buf, SLOT(s));
      __syncthreads();
      if (tid == 0)
        __hip_atomic_store(&f0[sub], s + 1, __ATOMIC_RELAXED, __HIP_MEMORY_SCOPE_AGENT);
    }
  } else {
    for (int j = 0; j < SLEN; ++j) {
      f32x16 acc = {0.f,0.f,0.f,0.f,0.f,0.f,0.f,0.f,0.f,0.f,0.f,0.f,0.f,0.f,0.f,0.f};
      // --- h1(j-1) part: ks = nt + 4jj, jj=16..31 (k in [1024,2048)) ---
      if (j > 0) {
        wave_wait(f1, j);
        const __bf16* hp1 = h1buf + SLOT(j - 1) + (size_t)arow * HDIM + koff8;
        #pragma unroll
        for (int jj = 16; jj < 32; ++jj) {
          int ks = nt + 4 * jj;
          bf16x8 a = hload<BIG>(hp1 + ks * 16 - HDIM);
          acc = MFMA32(a, LDSB(ks), acc);
        }
      }
      // --- h0'(j) part: ks = nt + 4jj, jj=0..15 (k in [0,1024)) ---
      wave_wait(f0, j + 1);
      {
        const __bf16* hp0 = h0buf + SLOT(j) + (size_t)arow * HDIM + koff8;
        #pragma unroll
        for (int jj = 0; jj < 16; ++jj) {
          int ks = nt + 4 * jj;
          bf16x8 a = hload<BIG>(hp0 + ks * 16);
          acc = MFMA32(a, LDSB(ks), acc);
        }
      }
      ZWRITE();
      __syncthreads();
      if constexpr (!BIG) {
        if (j >= RING) wave_wait(f1, j - RING + 2);
      }
      EPILOGUE(h1buf, SLOT(j));
      __syncthreads();
      if (tid == 0)
        __hip_atomic_store(&f1[sub], j + 1, __ATOMIC_RELAXED, __HIP_MEMORY_SCOPE_AGENT);
    }
  }
}

// ---- final FC: out[b] = sigmoid(h1(511) . fcw + fcb) ----
__global__ void fc_kernel(const __bf16* __restrict__ h1slot,
                          const float* __restrict__ fcw, const float* __restrict__ fcb,
                          float* __restrict__ out) {
  __shared__ float part[512];
  const int tid = threadIdx.x, b = tid >> 3, q2 = tid & 7;
  const __bf16* hr = h1slot + b * HDIM + q2 * 128;
  const float*  wr = fcw + q2 * 128;
  float acc = 0.0f;
  for (int k = 0; k < 128; k += 8) {
    bf16x8 hvv = *(const bf16x8*)(hr + k);   // fresh dispatch: caches invalidated
    #pragma unroll
    for (int i = 0; i < 8; ++i) acc += (float)hvv[i] * wr[k + i];
  }
  part[tid] = acc;
  __syncthreads();
  if (tid < BATCH) {
    float s = fcb[0];
    #pragma unroll
    for (int i = 0; i < 8; ++i) s += part[tid * 8 + i];
    out[tid] = 1.0f / (1.0f + __expf(-s));
  }
}

extern "C" void kernel_launch(void* const* d_in, const int* in_sizes, int n_in,
                              void* d_out, int out_size, void* d_ws, size_t ws_size,
                              hipStream_t stream) {
  (void)in_sizes; (void)n_in; (void)out_size;
  const int*   x   = (const int*)  d_in[0];
  const float* emb = (const float*)d_in[1];
  const float* Wx0 = (const float*)d_in[2];
  const float* bx0 = (const float*)d_in[3];
  const float* Wh0 = (const float*)d_in[4];
  const float* bh0 = (const float*)d_in[5];
  const float* Wx1 = (const float*)d_in[6];
  const float* bx1 = (const float*)d_in[7];
  const float* Wh1 = (const float*)d_in[8];
  const float* bh1 = (const float*)d_in[9];
  const float* fcw = (const float*)d_in[10];
  const float* fcb = (const float*)d_in[11];
  float* out = (float*)d_out;

  char* ws = (char*)d_ws;
  int* f0 = (int*)(ws);
  int* f1 = (int*)(ws + 512);

  const size_t need_big = 4096 + 2 * HBUF_BIG + XE_BYTES;           // ~160.1 MiB
  const size_t need_sml = 4096 + 2 * HBUF_SML + XE_BYTES;           // ~34.1 MiB
  const int big    = (ws_size >= need_big) ? 1 : 0;
  const size_t hbytes = big ? HBUF_BIG : HBUF_SML;
  __bf16* h0buf = (__bf16*)(ws + 4096);
  __bf16* h1buf = (__bf16*)(ws + 4096 + hbytes);
  __bf16* xe    = (__bf16*)(ws + 4096 + 2 * hbytes);
  const int use_xe = (big || ws_size >= need_sml) ? 1 : 0;

  hipMemsetAsync(d_ws, 0, 4096, stream);   // flags only
  if (use_xe) {
    const int groups = SLEN * BATCH * (EDIM / 8);
    xe_gather<<<(groups + 255) / 256, 256, 0, stream>>>(x, emb, xe);
  }
  if (big) {
    lstm_persistent<1><<<NBLK, 512, 0, stream>>>(x, emb, Wx0, bx0, Wh0, bh0,
                                                 Wx1, bx1, Wh1, bh1,
                                                 xe, use_xe, h0buf, h1buf, f0, f1);
    fc_kernel<<<1, 512, 0, stream>>>(h1buf + (size_t)(SLEN - 1) * HB, fcw, fcb, out);
  } else {
    lstm_persistent<0><<<NBLK, 512, 0, stream>>>(x, emb, Wx0, bx0, Wh0, bh0,
                                                 Wx1, bx1, Wh1, bh1,
                                                 xe, use_xe, h0buf, h1buf, f0, f1);
    fc_kernel<<<1, 512, 0, stream>>>(h1buf + (size_t)((SLEN - 1) & (RING - 1)) * HB, fcw, fcb, out);
  }
}

// Round 10
// 6398.735 us; speedup vs baseline: 2.7855x; 1.1207x over previous
//
#include <hip/hip_runtime.h>

// ---------------- problem constants ----------------
#define BATCH 64
#define SLEN  512
#define EDIM  512
#define HDIM  1024
#define NBLK  256
#define HALF  128                // blocks per layer group
#define K0    1536               // layer0 K  (xe 512 | h0 1024)
#define K1    2048               // layer1 K  (h0' 1024 | h1 1024)
#define ZST   68                 // zbuf row stride (f32): 2 nt-partials of 34
#define HB    (BATCH * HDIM)     // elems per h slot (128 KiB bf16)
#define RING  8                  // fallback ring depth

#define XE_BYTES ((size_t)SLEN * BATCH * EDIM * 2)      // 32 MiB
#define HBUF_BIG ((size_t)SLEN * HB * 2)                // 64 MiB per layer
#define HBUF_SML ((size_t)RING * HB * 2)                // 1 MiB per layer

typedef __bf16 bf16x8 __attribute__((ext_vector_type(8)));
typedef float  f32x4  __attribute__((ext_vector_type(4)));
typedef unsigned u32x4 __attribute__((ext_vector_type(4)));

__device__ __forceinline__ float sigm(float x) { return 1.0f / (1.0f + __expf(-x)); }
__device__ __forceinline__ float tanhfast(float x) {
  float e = __expf(-2.0f * __builtin_fabsf(x));
  float r = (1.0f - e) / (1.0f + e);
  return x < 0.0f ? -r : r;
}

// 16B write-through store (visible at L3 once vmcnt drains; never dirty in L2)
__device__ __forceinline__ void st16_wt(__bf16* p, unsigned d0, unsigned d1,
                                        unsigned d2, unsigned d3) {
  u32x4 v = {d0, d1, d2, d3};
  asm volatile("global_store_dwordx4 %0, %1, off sc0 sc1" :: "v"(p), "v"(v) : "memory");
}

// L2-bypassing 16B load (fallback ring path only)
__device__ __forceinline__ bf16x8 ald16(const __bf16* p) {
  union { unsigned long long q[2]; bf16x8 v; } u;
  u.q[0] = __hip_atomic_load((const unsigned long long*)p,       __ATOMIC_RELAXED, __HIP_MEMORY_SCOPE_AGENT);
  u.q[1] = __hip_atomic_load((const unsigned long long*)(p + 4), __ATOMIC_RELAXED, __HIP_MEMORY_SCOPE_AGENT);
  return u.v;
}

template<int BIG>
__device__ __forceinline__ bf16x8 hload(const __bf16* p) {
  if constexpr (BIG) return *(const bf16x8*)p;   // normal load: L2-cached, multicast
  else return ald16(p);                          // ring mode: must bypass (slot reuse)
}

// Per-wave wait: all lanes poll the 128 layer flags (2 per lane), s_sleep poll.
__device__ __forceinline__ void wave_wait(const int* f, int target) {
  if (target <= 0) return;
  const int l = threadIdx.x & 63;
  int tries = 0;
  while (true) {
    int v0 = __hip_atomic_load(f + l,      __ATOMIC_RELAXED, __HIP_MEMORY_SCOPE_AGENT);
    int v1 = __hip_atomic_load(f + l + 64, __ATOMIC_RELAXED, __HIP_MEMORY_SCOPE_AGENT);
    if (__all((v0 >= target) && (v1 >= target))) return;
    __builtin_amdgcn_s_sleep(1);
    if (++tries > (1 << 21)) return;   // anti-hang safety net
  }
}

// ---- xe = bf16(emb[x]) laid out [t][b][e] ----
__global__ void xe_gather(const int* __restrict__ x, const float* __restrict__ emb,
                          __bf16* __restrict__ xe) {
  int g = blockIdx.x * blockDim.x + threadIdx.x;
  if (g >= SLEN * BATCH * (EDIM / 8)) return;
  int e8 = g & 63, bt = g >> 6;
  int b = bt & 63, t = bt >> 6;
  int tok = x[b * SLEN + t];
  const float* er = emb + (size_t)tok * EDIM + e8 * 8;
  f32x4 v0 = *(const f32x4*)er, v1 = *(const f32x4*)(er + 4);
  bf16x8 o = { (__bf16)v0[0], (__bf16)v0[1], (__bf16)v0[2], (__bf16)v0[3],
               (__bf16)v1[0], (__bf16)v1[1], (__bf16)v1[2], (__bf16)v1[3] };
  *(bf16x8*)(xe + ((size_t)t * BATCH + b) * EDIM + e8 * 8) = o;
}

#define MFMA16(a, b, c) __builtin_amdgcn_mfma_f32_16x16x32_bf16(a, b, c, 0, 0, 0)

// Persistent skewed 2-layer LSTM. 16x16x32 MFMA (R5 geometry: optimal A-load
// coalescing), fragment-major LDS B (R9's zero-conflict layout), batch-issued
// A loads for memory-level parallelism. Waves: mt(4 batch tiles) x nt(2 K-split).
// B fragment (t, m32, lane) = W[zcol = t*16 + (lane&15)][k = m32*32 + (lane>>4)*8 + i]
// stored at ((t*64 + m32)*64 + lane)*16 -> per-MFMA wave read = linear 1KB burst.
template<int BIG>
__global__ __launch_bounds__(512, 2) void lstm_persistent(
    const int* __restrict__ x, const float* __restrict__ emb,
    const float* __restrict__ Wx0, const float* __restrict__ bx0,
    const float* __restrict__ Wh0, const float* __restrict__ bh0,
    const float* __restrict__ Wx1, const float* __restrict__ bx1,
    const float* __restrict__ Wh1, const float* __restrict__ bh1,
    const __bf16* __restrict__ xe, int use_xe,
    __bf16* h0buf, __bf16* h1buf, int* f0, int* f1)
{
  __shared__ __align__(16) unsigned char WsB[2 * 64 * 64 * 16];  // 128 KiB
  __shared__ float zbuf[BATCH * ZST];                            // 17 KiB
  __shared__ float bias[32];

  const int tid   = threadIdx.x;
  const int wg    = blockIdx.x;
  const int layer = wg >> 7;
  const int sub   = wg & (HALF - 1);

  // ---- stage weights into fragment-major LDS (linear 16B writes) ----
  {
    const int KS = layer ? 64 : 48;            // m32 steps
    for (int idx = tid; idx < 2 * KS * 64; idx += 512) {
      int t   = idx / (KS * 64);
      int r   = idx - t * (KS * 64);
      int m32 = r >> 6, ln = r & 63;
      int n   = t * 16 + (ln & 15);            // z-col 0..31
      int grow = (n >> 3) * HDIM + sub * 8 + (n & 7);
      int k   = m32 * 32 + (ln >> 4) * 8;
      const float* src;
      if (layer == 0) src = (k < EDIM) ? (Wx0 + (size_t)grow * EDIM + k)
                                       : (Wh0 + (size_t)grow * HDIM + (k - EDIM));
      else            src = (k < HDIM) ? (Wx1 + (size_t)grow * HDIM + k)
                                       : (Wh1 + (size_t)grow * HDIM + (k - HDIM));
      f32x4 v0 = *(const f32x4*)src, v1 = *(const f32x4*)(src + 4);
      bf16x8 o = { (__bf16)v0[0], (__bf16)v0[1], (__bf16)v0[2], (__bf16)v0[3],
                   (__bf16)v1[0], (__bf16)v1[1], (__bf16)v1[2], (__bf16)v1[3] };
      *(bf16x8*)(WsB + (size_t)((t * 64 + m32) * 64 + ln) * 16) = o;
    }
    if (tid < 32) {
      int grow = (tid >> 3) * HDIM + sub * 8 + (tid & 7);
      bias[tid] = layer ? (bx1[grow] + bh1[grow]) : (bx0[grow] + bh0[grow]);
    }
  }
  __syncthreads();

  const int lane = tid & 63, wave = tid >> 6;
  const int mrow = lane & 15;            // batch row within 16-tile / z-col within 16
  const int q    = lane >> 4;            // k-subgroup (8 elems)
  const int mt   = wave >> 1, nt = wave & 1;   // 4 batch tiles x 2 K-split halves
  const int brow = mt * 16 + mrow;
  const int bg   = tid >> 3, jl = tid & 7;
  const int zrow = mt * 16 + q * 4;

  float cst = 0.0f;

#define SLOT(s)  ((size_t)(BIG ? (s) : ((s) & (RING - 1))) * HB)
#define LDSB(t, m) (*(const bf16x8*)(&WsB[(size_t)(((t) * 64 + (m)) * 64 + lane) * 16]))

#define ZWRITE()                                                                  \
  do {                                                                            \
    _Pragma("unroll")                                                             \
    for (int r = 0; r < 4; ++r) {                                                 \
      zbuf[(zrow + r) * ZST + nt * 34 + mrow]      = acc0[r];                     \
      zbuf[(zrow + r) * ZST + nt * 34 + 16 + mrow] = acc1[r];                     \
    }                                                                             \
  } while (0)

#define EPILOGUE(hdst, slotExpr)                                                  \
  do {                                                                            \
    float zf = zbuf[bg*ZST +      jl] + zbuf[bg*ZST + 34 +      jl] + bias[     jl]; \
    float zi = zbuf[bg*ZST +  8 + jl] + zbuf[bg*ZST + 34 +  8 + jl] + bias[ 8 + jl]; \
    float zg = zbuf[bg*ZST + 16 + jl] + zbuf[bg*ZST + 34 + 16 + jl] + bias[16 + jl]; \
    float zo = zbuf[bg*ZST + 24 + jl] + zbuf[bg*ZST + 34 + 24 + jl] + bias[24 + jl]; \
    float fg = sigm(zf), ig = sigm(zi), gg = tanhfast(zg), og = sigm(zo);         \
    cst = fg * cst + ig * gg;                                                     \
    __bf16 hv = (__bf16)(og * tanhfast(cst));                                     \
    unsigned short us = __builtin_bit_cast(unsigned short, hv);                   \
    unsigned pw = ((unsigned)us) | (((unsigned)(unsigned short)__shfl_xor((int)us, 1, 64)) << 16); \
    unsigned d1 = (unsigned)__shfl_xor((int)pw, 2, 64);                           \
    unsigned d2 = (unsigned)__shfl_xor((int)pw, 4, 64);                           \
    unsigned d3 = (unsigned)__shfl_xor((int)pw, 6, 64);                           \
    if (jl == 0)                                                                  \
      st16_wt(hdst + (slotExpr) + bg * HDIM + sub * 8, pw, d1, d2, d3);           \
    asm volatile("s_waitcnt vmcnt(0)" ::: "memory");                              \
  } while (0)

  if (layer == 0) {
    for (int s = 0; s < SLEN; ++s) {
      f32x4 acc0 = {0.f,0.f,0.f,0.f}, acc1 = {0.f,0.f,0.f,0.f};
      // --- issue xe A-loads (no cross-block dep) BEFORE the flag wait ---
      bf16x8 ax[8];
      if (use_xe) {
        const __bf16* aX = xe + ((size_t)s * BATCH + brow) * EDIM + q * 8;
        #pragma unroll
        for (int jj = 0; jj < 8; ++jj) ax[jj] = *(const bf16x8*)(aX + (nt + 2*jj) * 32);
      } else {
        const int tok = x[brow * SLEN + s];
        const float* erow = emb + (size_t)tok * EDIM + q * 8;
        #pragma unroll
        for (int jj = 0; jj < 8; ++jj) {
          f32x4 e0 = *(const f32x4*)(erow + (nt + 2*jj) * 32);
          f32x4 e1 = *(const f32x4*)(erow + (nt + 2*jj) * 32 + 4);
          ax[jj] = (bf16x8){ (__bf16)e0[0], (__bf16)e0[1], (__bf16)e0[2], (__bf16)e0[3],
                             (__bf16)e1[0], (__bf16)e1[1], (__bf16)e1[2], (__bf16)e1[3] };
        }
      }
      // --- flag wait, then batch-issue all 16 h A-loads ---
      bf16x8 ah[16];
      if (s > 0) {
        wave_wait(f0, s);
        const __bf16* hp = h0buf + SLOT(s - 1) + (size_t)brow * HDIM + q * 8;
        #pragma unroll
        for (int jj = 0; jj < 16; ++jj) ah[jj] = hload<BIG>(hp + (nt + 2*jj) * 32);
      }
      // --- MFMA chains (2 independent accs; loads complete underneath) ---
      #pragma unroll
      for (int jj = 0; jj < 8; ++jj) {
        const int m = nt + 2*jj;
        acc0 = MFMA16(ax[jj], LDSB(0, m), acc0);
        acc1 = MFMA16(ax[jj], LDSB(1, m), acc1);
      }
      if (s > 0) {
        #pragma unroll
        for (int jj = 0; jj < 16; ++jj) {
          const int m = 16 + nt + 2*jj;     // k in [512, 1536)
          acc0 = MFMA16(ah[jj], LDSB(0, m), acc0);
          acc1 = MFMA16(ah[jj], LDSB(1, m), acc1);
        }
      }
      ZWRITE();
      __syncthreads();
      if constexpr (!BIG) {   // ring anti-dep: slot reused after RING steps
        if (s >= RING) { wave_wait(f1, s - RING + 2); wave_wait(f0, s - RING + 2); }
      }
      EPILOGUE(h0buf, SLOT(s));
      __syncthreads();
      if (tid == 0)
        __hip_atomic_store(&f0[sub], s + 1, __ATOMIC_RELAXED, __HIP_MEMORY_SCOPE_AGENT);
    }
  } else {
    for (int j = 0; j < SLEN; ++j) {
      f32x4 acc0 = {0.f,0.f,0.f,0.f}, acc1 = {0.f,0.f,0.f,0.f};
      // --- h1(j-1): wait (earlier event), batch-issue loads ---
      bf16x8 a1[16];
      if (j > 0) {
        wave_wait(f1, j);
        const __bf16* hp1 = h1buf + SLOT(j - 1) + (size_t)brow * HDIM + q * 8;
        #pragma unroll
        for (int jj = 0; jj < 16; ++jj) a1[jj] = hload<BIG>(hp1 + (nt + 2*jj) * 32);
      }
      // --- h0'(j): wait (later event), batch-issue loads ---
      wave_wait(f0, j + 1);
      bf16x8 a0[16];
      {
        const __bf16* hp0 = h0buf + SLOT(j) + (size_t)brow * HDIM + q * 8;
        #pragma unroll
        for (int jj = 0; jj < 16; ++jj) a0[jj] = hload<BIG>(hp0 + (nt + 2*jj) * 32);
      }
      // --- MFMA chains: h0' occupies m32 0..31, h1 occupies 32..63 ---
      #pragma unroll
      for (int jj = 0; jj < 16; ++jj) {
        const int m = nt + 2*jj;
        acc0 = MFMA16(a0[jj], LDSB(0, m), acc0);
        acc1 = MFMA16(a0[jj], LDSB(1, m), acc1);
      }
      if (j > 0) {
        #pragma unroll
        for (int jj = 0; jj < 16; ++jj) {
          const int m = 32 + nt + 2*jj;
          acc0 = MFMA16(a1[jj], LDSB(0, m), acc0);
          acc1 = MFMA16(a1[jj], LDSB(1, m), acc1);
        }
      }
      ZWRITE();
      __syncthreads();
      if constexpr (!BIG) {
        if (j >= RING) wave_wait(f1, j - RING + 2);
      }
      EPILOGUE(h1buf, SLOT(j));
      __syncthreads();
      if (tid == 0)
        __hip_atomic_store(&f1[sub], j + 1, __ATOMIC_RELAXED, __HIP_MEMORY_SCOPE_AGENT);
    }
  }
}

// ---- final FC: out[b] = sigmoid(h1(511) . fcw + fcb) ----
__global__ void fc_kernel(const __bf16* __restrict__ h1slot,
                          const float* __restrict__ fcw, const float* __restrict__ fcb,
                          float* __restrict__ out) {
  __shared__ float part[512];
  const int tid = threadIdx.x, b = tid >> 3, q2 = tid & 7;
  const __bf16* hr = h1slot + b * HDIM + q2 * 128;
  const float*  wr = fcw + q2 * 128;
  float acc = 0.0f;
  for (int k = 0; k < 128; k += 8) {
    bf16x8 hvv = *(const bf16x8*)(hr + k);   // fresh dispatch: caches invalidated
    #pragma unroll
    for (int i = 0; i < 8; ++i) acc += (float)hvv[i] * wr[k + i];
  }
  part[tid] = acc;
  __syncthreads();
  if (tid < BATCH) {
    float s = fcb[0];
    #pragma unroll
    for (int i = 0; i < 8; ++i) s += part[tid * 8 + i];
    out[tid] = 1.0f / (1.0f + __expf(-s));
  }
}

extern "C" void kernel_launch(void* const* d_in, const int* in_sizes, int n_in,
                              void* d_out, int out_size, void* d_ws, size_t ws_size,
                              hipStream_t stream) {
  (void)in_sizes; (void)n_in; (void)out_size;
  const int*   x   = (const int*)  d_in[0];
  const float* emb = (const float*)d_in[1];
  const float* Wx0 = (const float*)d_in[2];
  const float* bx0 = (const float*)d_in[3];
  const float* Wh0 = (const float*)d_in[4];
  const float* bh0 = (const float*)d_in[5];
  const float* Wx1 = (const float*)d_in[6];
  const float* bx1 = (const float*)d_in[7];
  const float* Wh1 = (const float*)d_in[8];
  const float* bh1 = (const float*)d_in[9];
  const float* fcw = (const float*)d_in[10];
  const float* fcb = (const float*)d_in[11];
  float* out = (float*)d_out;

  char* ws = (char*)d_ws;
  int* f0 = (int*)(ws);
  int* f1 = (int*)(ws + 512);

  const size_t need_big = 4096 + 2 * HBUF_BIG + XE_BYTES;           // ~160.1 MiB
  const size_t need_sml = 4096 + 2 * HBUF_SML + XE_BYTES;           // ~34.1 MiB
  const int big    = (ws_size >= need_big) ? 1 : 0;
  const size_t hbytes = big ? HBUF_BIG : HBUF_SML;
  __bf16* h0buf = (__bf16*)(ws + 4096);
  __bf16* h1buf = (__bf16*)(ws + 4096 + hbytes);
  __bf16* xe    = (__bf16*)(ws + 4096 + 2 * hbytes);
  const int use_xe = (big || ws_size >= need_sml) ? 1 : 0;

  hipMemsetAsync(d_ws, 0, 4096, stream);   // flags only
  if (use_xe) {
    const int groups = SLEN * BATCH * (EDIM / 8);
    xe_gather<<<(groups + 255) / 256, 256, 0, stream>>>(x, emb, xe);
  }
  if (big) {
    lstm_persistent<1><<<NBLK, 512, 0, stream>>>(x, emb, Wx0, bx0, Wh0, bh0,
                                                 Wx1, bx1, Wh1, bh1,
                                                 xe, use_xe, h0buf, h1buf, f0, f1);
    fc_kernel<<<1, 512, 0, stream>>>(h1buf + (size_t)(SLEN - 1) * HB, fcw, fcb, out);
  } else {
    lstm_persistent<0><<<NBLK, 512, 0, stream>>>(x, emb, Wx0, bx0, Wh0, bh0,
                                                 Wx1, bx1, Wh1, bh1,
                                                 xe, use_xe, h0buf, h1buf, f0, f1);
    fc_kernel<<<1, 512, 0, stream>>>(h1buf + (size_t)((SLEN - 1) & (RING - 1)) * HB, fcw, fcb, out);
  }
}